// Round 26
// baseline (192.739 us; speedup 1.0000x reference)
//
#include <hip/hip_runtime.h>

typedef __attribute__((ext_vector_type(8))) short bf16x8;
typedef __attribute__((ext_vector_type(4))) float f32x4;

__device__ __forceinline__ unsigned short f2bf(float f) {
  unsigned int u = __builtin_bit_cast(unsigned int, f);
  u += 0x7fffu + ((u >> 16) & 1u);   // RNE
  return (unsigned short)(u >> 16);
}

#define GLD16(gp, lp) __builtin_amdgcn_global_load_lds( \
    (const __attribute__((address_space(1))) unsigned int*)(gp), \
    (__attribute__((address_space(3))) unsigned int*)(lp), 16, 0, 0)

// ---------------------------------------------------------------------------
// Grid-stride prep (r21-verified): wide-load mask pack + converts + weights.
__global__ __launch_bounds__(256) void prep_all(
    const unsigned char* __restrict__ m, unsigned long long* __restrict__ pm,
    const float* __restrict__ query, const float* __restrict__ node,
    const float* __restrict__ wq, const float* __restrict__ wk,
    const float* __restrict__ wv,
    unsigned short* __restrict__ Xq, unsigned short* __restrict__ Xn,
    unsigned short* __restrict__ wqb, unsigned short* __restrict__ wkb,
    unsigned short* __restrict__ wvt, float* __restrict__ sums)
{
  const int b = blockIdx.x;          // 0..2047
  const int t = threadIdx.x;
  __shared__ unsigned long long ldsw[256];
  __shared__ int mode1;

  if (t == 0) mode1 = 0;
  __syncthreads();
  const unsigned int* m32 = (const unsigned int*)m;
  unsigned int pw = m32[(size_t)b * 4096 + t];
  if (pw & 0x0000ff00u) mode1 = 1;   // benign race
  __syncthreads();

  {
    const int wv_ = t >> 6;
    const int l = t & 63;
    const long gbase = (long)b * 256 + wv_ * 64;
    if (mode1) {
#pragma unroll
      for (int i = 0; i < 4; ++i) {
        const uint4 v = *(const uint4*)(m + ((size_t)(gbase + i * 16) * 64) + (size_t)l * 16);
        unsigned int ws_[4] = {v.x, v.y, v.z, v.w};
        unsigned int bits16 = 0;
#pragma unroll
        for (int q = 0; q < 4; ++q)
#pragma unroll
          for (int bb = 0; bb < 4; ++bb)
            if ((ws_[q] >> (8 * bb)) & 0xffu) bits16 |= 1u << (q * 4 + bb);
        unsigned long long part = (unsigned long long)bits16 << (16 * (l & 3));
        part |= __shfl_xor(part, 1);
        part |= __shfl_xor(part, 2);
        if ((l & 3) == 0) ldsw[wv_ * 64 + i * 16 + (l >> 2)] = part;
      }
    } else {
#pragma unroll
      for (int i = 0; i < 16; ++i) {
        const uint4 v = *(const uint4*)(m32 + ((size_t)(gbase + i * 4) * 64) + (size_t)l * 4);
        unsigned int nib = (v.x ? 1u : 0u) | (v.y ? 2u : 0u) |
                           (v.z ? 4u : 0u) | (v.w ? 8u : 0u);
        unsigned long long part = (unsigned long long)nib << (4 * (l & 15));
        part |= __shfl_xor(part, 1);
        part |= __shfl_xor(part, 2);
        part |= __shfl_xor(part, 4);
        part |= __shfl_xor(part, 8);
        if ((l & 15) == 0) ldsw[wv_ * 64 + i * 4 + (l >> 4)] = part;
      }
    }
  }
  __syncthreads();
  pm[(long)b * 256 + t] = ldsw[t];

  {
    const int stride = 2048 * 256;
#pragma unroll
    for (int r = 0; r < 8; ++r) {
      int i = b * 256 + t + r * stride;
      const float* src;
      unsigned short* dst;
      int j;
      if (i < 2097152) { src = query; dst = Xq; j = i; }
      else             { src = node;  dst = Xn; j = i - 2097152; }
      float4 v = ((const float4*)src)[j];
      ushort4 o;
      o.x = f2bf(v.x); o.y = f2bf(v.y); o.z = f2bf(v.z); o.w = f2bf(v.w);
      ((ushort4*)dst)[j] = o;
    }
  }

  for (int idx = b * 256 + t; idx < 786432; idx += 2048 * 256) {
    int w = idx >> 18;
    int rem = idx & 262143;
    if (w == 0)      wqb[rem] = f2bf(wq[rem]);
    else if (w == 1) wkb[rem] = f2bf(wk[rem]);
    else {
      int n = rem >> 9, k = rem & 511;
      wvt[n * 512 + k] = f2bf(wv[k * 512 + n]);
    }
  }

  {
    int idx = b * 256 + t;
    if (idx < 16384) sums[idx] = 0.0f;
  }
}

// ---------------------------------------------------------------------------
// Unified 128x128 core, 3 blocks/CU (r12/r14/r15-verified). bf16 out.
// Kept for the tiny MT GEMM only.
__device__ __forceinline__ void core128(
    const unsigned short* __restrict__ Ab, const unsigned short* __restrict__ Bb,
    void* __restrict__ Cb, long ldA, long ldB, long ldO, int nk,
    long bm, long bn, char* smem)
{
  const int tid = threadIdx.x;
  const int lane = tid & 63;
  const int wid = tid >> 6;
  const int wr = wid >> 1, wc = wid & 1;
  const int fr = lane & 15, fq = lane >> 4;

  const int srow = tid >> 2;
  const int sch = (tid & 3) ^ ((srow >> 1) & 3);

  char* bufs[3] = { smem, smem + 16384, smem + 32768 };

#define STAGE_C(buf, kt) do { \
    const long k0_ = (long)(kt) << 5; \
    GLD16(Ab + (bm + srow) * ldA + k0_ + sch * 8,        (buf) + tid * 16); \
    GLD16(Ab + (bm + 64 + srow) * ldA + k0_ + sch * 8,   (buf) + 4096 + tid * 16); \
    GLD16(Bb + (bn + srow) * ldB + k0_ + sch * 8,        (buf) + 8192 + tid * 16); \
    GLD16(Bb + (bn + 64 + srow) * ldB + k0_ + sch * 8,   (buf) + 12288 + tid * 16); \
  } while (0)

  int aoff[4], boff[4];
#pragma unroll
  for (int i = 0; i < 4; ++i) {
    const int ra = wr * 64 + i * 16 + fr;
    aoff[i] = ra * 64 + (fq ^ ((ra >> 1) & 3)) * 16;
    const int rb = wc * 64 + i * 16 + fr;
    boff[i] = 8192 + rb * 64 + (fq ^ ((rb >> 1) & 3)) * 16;
  }

  f32x4 acc[4][4] = {};

  STAGE_C(bufs[0], 0);
  STAGE_C(bufs[1], 1);
  char* c0 = bufs[0]; char* c1 = bufs[1]; char* c2 = bufs[2];

  for (int t = 0; t < nk; ++t) {
    __builtin_amdgcn_sched_barrier(0);
    __builtin_amdgcn_s_barrier();
    if (t + 2 < nk) {
      STAGE_C(c2, t + 2);
      asm volatile("s_waitcnt vmcnt(8)" ::: "memory");
    } else if (t + 2 == nk) {
      asm volatile("s_waitcnt vmcnt(4)" ::: "memory");
    } else {
      asm volatile("s_waitcnt vmcnt(0)" ::: "memory");
    }
    __builtin_amdgcn_s_barrier();
    __builtin_amdgcn_sched_barrier(0);

    bf16x8 a[4];
#pragma unroll
    for (int mi = 0; mi < 4; ++mi)
      a[mi] = *(const bf16x8*)(c0 + aoff[mi]);
    __builtin_amdgcn_s_setprio(1);
#pragma unroll
    for (int nj = 0; nj < 4; ++nj) {
      const bf16x8 b = *(const bf16x8*)(c0 + boff[nj]);
#pragma unroll
      for (int mi = 0; mi < 4; ++mi)
        acc[mi][nj] = __builtin_amdgcn_mfma_f32_16x16x32_bf16(a[mi], b, acc[mi][nj], 0, 0, 0);
    }
    __builtin_amdgcn_s_setprio(0);

    char* tmp = c0; c0 = c1; c1 = c2; c2 = tmp;
  }
#undef STAGE_C

  unsigned short* C = (unsigned short*)Cb;
#pragma unroll
  for (int mi = 0; mi < 4; ++mi)
#pragma unroll
    for (int nj = 0; nj < 4; ++nj) {
      const long row = bm + wr * 64 + mi * 16 + fq * 4;
      const long col = bn + wc * 64 + nj * 16 + fr;
#pragma unroll
      for (int r = 0; r < 4; ++r)
        C[(row + r) * ldO + col] = f2bf(acc[mi][nj][r]);
    }
}

// ---------------------------------------------------------------------------
// Wide core (r22/r23-verified): 128(A) x 256(B) tile, BK=32, 4 waves,
// acc[4][8] = 32 MFMA/barrier-pair, 3 bufs x 24KB = 72KB -> 2 blocks/CU.
// Stage t+2; vmcnt ledger 12/6/0 (L=6).
// mode 0: bf16 out. mode 1: scores epilogue (bitmask exp + rowsum atomics).
__device__ __forceinline__ void core_wide(
    const unsigned short* __restrict__ Ab, const unsigned short* __restrict__ Bb,
    void* __restrict__ Cb, long ldA, long ldB, long ldO, int nk,
    long bm, long bn, char* smem, int mode,
    const unsigned long long* __restrict__ pmask, float* __restrict__ sumz)
{
  const int tid = threadIdx.x;
  const int lane = tid & 63;
  const int wid = tid >> 6;
  const int wr = wid >> 1, wc = wid & 1;
  const int fr = lane & 15, fq = lane >> 4;

  const int srow = tid >> 2;                    // 0..63
  const int sch = (tid & 3) ^ ((srow >> 1) & 3);

  char* bufs[3] = { smem, smem + 24576, smem + 49152 };

#define STAGE_W(buf, kt) do { \
    const long k0_ = (long)(kt) << 5; \
    GLD16(Ab + (bm + srow) * ldA + k0_ + sch * 8,        (buf) + tid * 16); \
    GLD16(Ab + (bm + 64 + srow) * ldA + k0_ + sch * 8,   (buf) + 4096 + tid * 16); \
    GLD16(Bb + (bn + srow) * ldB + k0_ + sch * 8,        (buf) + 8192 + tid * 16); \
    GLD16(Bb + (bn + 64 + srow) * ldB + k0_ + sch * 8,   (buf) + 12288 + tid * 16); \
    GLD16(Bb + (bn + 128 + srow) * ldB + k0_ + sch * 8,  (buf) + 16384 + tid * 16); \
    GLD16(Bb + (bn + 192 + srow) * ldB + k0_ + sch * 8,  (buf) + 20480 + tid * 16); \
  } while (0)

  int aoff[4], boff[8];
#pragma unroll
  for (int i = 0; i < 4; ++i) {
    const int r = wr * 64 + i * 16 + fr;
    aoff[i] = r * 64 + (fq ^ ((r >> 1) & 3)) * 16;
  }
#pragma unroll
  for (int i = 0; i < 8; ++i) {
    const int r = wc * 128 + i * 16 + fr;
    boff[i] = 8192 + r * 64 + (fq ^ ((r >> 1) & 3)) * 16;
  }

  f32x4 acc[4][8] = {};

  STAGE_W(bufs[0], 0);
  STAGE_W(bufs[1], 1);
  char* c0 = bufs[0]; char* c1 = bufs[1]; char* c2 = bufs[2];

  for (int t = 0; t < nk; ++t) {
    __builtin_amdgcn_sched_barrier(0);
    __builtin_amdgcn_s_barrier();               // B1: reads of c2's old tile done
    if (t + 2 < nk) {
      STAGE_W(c2, t + 2);
      asm volatile("s_waitcnt vmcnt(12)" ::: "memory");   // tile t landed
    } else if (t + 2 == nk) {
      asm volatile("s_waitcnt vmcnt(6)" ::: "memory");
    } else {
      asm volatile("s_waitcnt vmcnt(0)" ::: "memory");
    }
    __builtin_amdgcn_s_barrier();               // B2: tile t visible
    __builtin_amdgcn_sched_barrier(0);

    bf16x8 a[4];
#pragma unroll
    for (int mi = 0; mi < 4; ++mi)
      a[mi] = *(const bf16x8*)(c0 + aoff[mi]);
    __builtin_amdgcn_s_setprio(1);
#pragma unroll
    for (int nj = 0; nj < 8; ++nj) {
      const bf16x8 b = *(const bf16x8*)(c0 + boff[nj]);
#pragma unroll
      for (int mi = 0; mi < 4; ++mi)
        acc[mi][nj] = __builtin_amdgcn_mfma_f32_16x16x32_bf16(a[mi], b, acc[mi][nj], 0, 0, 0);
    }
    __builtin_amdgcn_s_setprio(0);

    char* tmp = c0; c0 = c1; c1 = c2; c2 = tmp;
  }
#undef STAGE_W

  // Epilogue. C/D layout: col=lane&15, row=(lane>>4)*4+r  [m89-verified]
  const float SCALE = 0.04419417382415922f;  // 1/sqrt(512)
  if (mode == 0) {
    unsigned short* C = (unsigned short*)Cb;
#pragma unroll
    for (int mi = 0; mi < 4; ++mi) {
      const long rowb = bm + wr * 64 + mi * 16 + fq * 4;
#pragma unroll
      for (int r = 0; r < 4; ++r) {
        const long row = rowb + r;
        unsigned short* Crow = C + row * ldO + bn + wc * 128 + fr;
#pragma unroll
        for (int ni = 0; ni < 8; ++ni)
          Crow[ni * 16] = f2bf(acc[mi][ni][r]);
      }
    }
  } else {
    unsigned short* C = (unsigned short*)Cb;
    const long wbase = (bn >> 6) + wc * 2;
#pragma unroll
    for (int mi = 0; mi < 4; ++mi) {
      const long rowb = bm + wr * 64 + mi * 16 + fq * 4;
#pragma unroll
      for (int r = 0; r < 4; ++r) {
        const long row = rowb + r;
        const unsigned long long w0 = pmask[row * 32 + wbase];
        const unsigned long long w1 = pmask[row * 32 + wbase + 1];
        unsigned short* Crow = C + row * ldO + bn + wc * 128 + fr;
        float s = 0.f;
#pragma unroll
        for (int ni = 0; ni < 8; ++ni) {
          const unsigned long long w = (ni < 4) ? w0 : w1;
          const int sh = (ni & 3) * 16 + fr;
          float e = ((w >> sh) & 1ull) ? 0.0f : __expf(acc[mi][ni][r] * SCALE);
          s += e;
          Crow[ni * 16] = f2bf(e);
        }
        s += __shfl_xor(s, 1); s += __shfl_xor(s, 2);
        s += __shfl_xor(s, 4); s += __shfl_xor(s, 8);
        if (fr == 0) atomicAdd(&sumz[row], s);
      }
    }
  }
}

// MT = Wk_bf * Wq_bf^T. grid(4,4,1).
__global__ __launch_bounds__(256, 3) void gemm_mt(
    const unsigned short* __restrict__ wkb, const unsigned short* __restrict__ wqb,
    unsigned short* __restrict__ MT)
{
  extern __shared__ char smem[];
  core128(wkb, wqb, MT, 512, 512, 512, 16,
          (long)blockIdx.x * 128, (long)blockIdx.y * 128, smem);
}

// Projections on the wide core, grid(128,2,2) = 512 blocks = 1 even round:
//  z=0: T = Xq*MT^T [16384x512]: bm=x*128, bn=y*256
//  z=1: Vt = Wvt*Xn^T [512x16384]: flat=x*2+y: bm=(flat>>6)*128, bn=(flat&63)*256
__global__ __launch_bounds__(256, 2) void gemm_proj(
    const unsigned short* __restrict__ Xq, const unsigned short* __restrict__ Xn,
    const unsigned short* __restrict__ MT, const unsigned short* __restrict__ Wvt,
    unsigned short* __restrict__ T, unsigned short* __restrict__ Vt)
{
  extern __shared__ char smem[];
  if (blockIdx.z == 0) {
    core_wide(Xq, MT, T, 512, 512, 512, 16,
              (long)blockIdx.x * 128, (long)blockIdx.y * 256, smem, 0,
              nullptr, nullptr);
  } else {
    const int flat = blockIdx.x * 2 + blockIdx.y;   // 0..255
    core_wide(Wvt, Xn, Vt, 512, 512, 16384, 16,
              (long)(flat >> 6) * 128, (long)(flat & 63) * 256, smem, 0,
              nullptr, nullptr);
  }
}

// Scores (r22-verified): 128x256 tile. grid(8,16,8): x=batch=XCD, y=q, z=kv.
__global__ __launch_bounds__(256, 2) void gemm_scores(
    const unsigned short* __restrict__ Tg, const unsigned short* __restrict__ Xng,
    unsigned short* __restrict__ Eg, const unsigned long long* __restrict__ pm,
    float* __restrict__ sums)
{
  extern __shared__ char smem[];
  const long z = blockIdx.x;
  core_wide(Tg + z * 1048576, Xng + z * 1048576, Eg + z * 4194304,
            512, 512, 2048, 16,
            (long)blockIdx.y * 128, (long)blockIdx.z * 256, smem, 1,
            pm + z * 65536, sums + z * 2048);
}

// ---------------------------------------------------------------------------
// PV: O = (E @ V) / rowsum, f32. Tile 64q x 256d, BK=32, 4 waves (2x2,
// each 32x128, acc[2][8] = 32 MFMA/barrier-pair), 3 bufs x 20KB = 60KB
// -> 2 blocks/CU. grid(8,2,32) = 512 blocks = FULL residency at 2/CU
// (fixes r23's 1-resident-block cancellation while keeping amortization).
// Stage t+2; L=5 loads/thread/tile; vmcnt ledger 10/5/0.
__global__ __launch_bounds__(256, 2) void gemm_pv(
    const unsigned short* __restrict__ E, const unsigned short* __restrict__ Vt,
    const float* __restrict__ sums, float* __restrict__ O)
{
  extern __shared__ char smem[];
  const long z = blockIdx.x;                    // batch = XCD
  const unsigned short* Ab = E + z * 4194304;   // ldA = 2048
  const unsigned short* Bb = Vt + z * 2048;     // ldB = 16384
  float* C = O + z * 1048576;
  const float* sums_ro = sums + z * 2048;
  const long bm = (long)blockIdx.z * 64;        // q panel (slow)
  const long bn = (long)blockIdx.y * 256;       // d panel (fast)

  const int tid = threadIdx.x;
  const int lane = tid & 63;
  const int wid = tid >> 6;
  const int wr = wid >> 1, wc = wid & 1;        // wave: 32q x 128d
  const int fr = lane & 15, fq = lane >> 4;

  const int srow = tid >> 2;                    // 0..63
  const int sch = (tid & 3) ^ ((srow >> 1) & 3);

  char* bufs[3] = { smem, smem + 20480, smem + 40960 };

#define STAGE_P(buf, kt) do { \
    const long k0_ = (long)(kt) << 5; \
    GLD16(Ab + (bm + (srow >> 1)) * 2048 + k0_ + ((tid & 7) ^ (((srow >> 1) >> 1) & 3) * 0 + (tid & 7) * 0 + sch) * 8, (buf)); \
  } while (0)
#undef STAGE_P
  // A tile: 64 rows x 32 cols = 4KB = 1 load/thread (srow 0..63, sch chunk).
  // B tile: 256 rows x 32 cols = 16KB = 4 loads/thread at rows +0/64/128/192.
#define STAGE_P(buf, kt) do { \
    const long k0_ = (long)(kt) << 5; \
    GLD16(Ab + (bm + srow) * 2048 + k0_ + sch * 8,       (buf) + tid * 16); \
    GLD16(Bb + (bn + srow) * 16384 + k0_ + sch * 8,      (buf) + 4096 + tid * 16); \
    GLD16(Bb + (bn + 64 + srow) * 16384 + k0_ + sch * 8, (buf) + 8192 + tid * 16); \
    GLD16(Bb + (bn + 128 + srow) * 16384 + k0_ + sch * 8,(buf) + 12288 + tid * 16); \
    GLD16(Bb + (bn + 192 + srow) * 16384 + k0_ + sch * 8,(buf) + 16384 + tid * 16); \
  } while (0)

  int aoff[2], boff[8];
#pragma unroll
  for (int i = 0; i < 2; ++i) {
    const int r = wr * 32 + i * 16 + fr;
    aoff[i] = r * 64 + (fq ^ ((r >> 1) & 3)) * 16;
  }
#pragma unroll
  for (int i = 0; i < 8; ++i) {
    const int r = wc * 128 + i * 16 + fr;
    boff[i] = 4096 + r * 64 + (fq ^ ((r >> 1) & 3)) * 16;
  }

  f32x4 acc[2][8] = {};

  STAGE_P(bufs[0], 0);
  STAGE_P(bufs[1], 1);
  char* c0 = bufs[0]; char* c1 = bufs[1]; char* c2 = bufs[2];

  const int nk = 64;
  for (int t = 0; t < nk; ++t) {
    __builtin_amdgcn_sched_barrier(0);
    __builtin_amdgcn_s_barrier();               // B1: reads of c2's old tile done
    if (t + 2 < nk) {
      STAGE_P(c2, t + 2);
      asm volatile("s_waitcnt vmcnt(10)" ::: "memory");   // tile t landed
    } else if (t + 2 == nk) {
      asm volatile("s_waitcnt vmcnt(5)" ::: "memory");
    } else {
      asm volatile("s_waitcnt vmcnt(0)" ::: "memory");
    }
    __builtin_amdgcn_s_barrier();               // B2: tile t visible
    __builtin_amdgcn_sched_barrier(0);

    bf16x8 a[2];
#pragma unroll
    for (int mi = 0; mi < 2; ++mi)
      a[mi] = *(const bf16x8*)(c0 + aoff[mi]);
    __builtin_amdgcn_s_setprio(1);
#pragma unroll
    for (int nj = 0; nj < 8; ++nj) {
      const bf16x8 b = *(const bf16x8*)(c0 + boff[nj]);
#pragma unroll
      for (int mi = 0; mi < 2; ++mi)
        acc[mi][nj] = __builtin_amdgcn_mfma_f32_16x16x32_bf16(a[mi], b, acc[mi][nj], 0, 0, 0);
    }
    __builtin_amdgcn_s_setprio(0);

    char* tmp = c0; c0 = c1; c1 = c2; c2 = tmp;
  }
#undef STAGE_P

  // Epilogue: O[q][d] = acc / sums[q]
#pragma unroll
  for (int mi = 0; mi < 2; ++mi) {
    const long rowb = bm + wr * 32 + mi * 16 + fq * 4;
#pragma unroll
    for (int r = 0; r < 4; ++r) {
      const long row = rowb + r;
      const float iv = 1.0f / sums_ro[row];
      float* Crow = C + row * 512 + bn + wc * 128 + fr;
#pragma unroll
      for (int ni = 0; ni < 8; ++ni)
        Crow[ni * 16] = acc[mi][ni][r] * iv;
    }
  }
}

// ---------------------------------------------------------------------------
extern "C" void kernel_launch(void* const* d_in, const int* in_sizes, int n_in,
                              void* d_out, int out_size, void* d_ws, size_t ws_size,
                              hipStream_t stream) {
  const float* node  = (const float*)d_in[0];
  const float* query = (const float*)d_in[1];
  const unsigned char* mask = (const unsigned char*)d_in[2];
  const float* wq = (const float*)d_in[3];
  const float* wk = (const float*)d_in[4];
  const float* wv = (const float*)d_in[5];
  float* out = (float*)d_out;

  char* ws = (char*)d_ws;
  unsigned short* T   = (unsigned short*)(ws);
  unsigned short* Xn  = (unsigned short*)(ws + 16777216);
  unsigned short* Vt  = (unsigned short*)(ws + 33554432);
  unsigned short* E   = (unsigned short*)(ws + 50331648);
  unsigned short* Xq  = (unsigned short*)(ws + 50331648);           // dead after T-proj
  unsigned short* wqb = (unsigned short*)(ws + 67108864);
  unsigned short* wkb = (unsigned short*)(ws + 67633152);
  unsigned short* Wvt = (unsigned short*)(ws + 68157440);
  unsigned short* MT  = (unsigned short*)(ws + 68681728);
  float* sums = (float*)(ws + 117440512);
  unsigned long long* pm = (unsigned long long*)(ws + 118489088);

  prep_all<<<2048, 256, 0, stream>>>(mask, pm, query, node, wq, wk, wv,
                                     Xq, Xn, wqb, wkb, Wvt, sums);

  gemm_mt<<<dim3(4, 4, 1), 256, 49152, stream>>>(wkb, wqb, MT);

  // Projections on the wide core: 512 blocks = exactly 1 round at 2/CU
  dim3 gp(128, 2, 2);
  gemm_proj<<<gp, 256, 73728, stream>>>(Xq, Xn, MT, Wvt, T, Vt);

  // Scores: 128x256 tile (r22-verified)
  dim3 gs(8, 16, 8);
  gemm_scores<<<gs, 256, 73728, stream>>>(T, Xn, E, pm, sums);

  // PV: 64x256 tile, 512 blocks = full residency at 2/CU, d-panel fastest
  dim3 gv(8, 2, 32);
  gemm_pv<<<gv, 256, 61440, stream>>>(E, Vt, sums, out);
}

// Round 27
// 185.095 us; speedup vs baseline: 1.0413x; 1.0413x over previous
//
#include <hip/hip_runtime.h>

typedef __attribute__((ext_vector_type(8))) short bf16x8;
typedef __attribute__((ext_vector_type(4))) float f32x4;

__device__ __forceinline__ unsigned short f2bf(float f) {
  unsigned int u = __builtin_bit_cast(unsigned int, f);
  u += 0x7fffu + ((u >> 16) & 1u);   // RNE
  return (unsigned short)(u >> 16);
}

#define GLD16(gp, lp) __builtin_amdgcn_global_load_lds( \
    (const __attribute__((address_space(1))) unsigned int*)(gp), \
    (__attribute__((address_space(3))) unsigned int*)(lp), 16, 0, 0)

// ---------------------------------------------------------------------------
// Grid-stride prep (r21-verified): wide-load mask pack + converts + weights.
__global__ __launch_bounds__(256) void prep_all(
    const unsigned char* __restrict__ m, unsigned long long* __restrict__ pm,
    const float* __restrict__ query, const float* __restrict__ node,
    const float* __restrict__ wq, const float* __restrict__ wk,
    const float* __restrict__ wv,
    unsigned short* __restrict__ Xq, unsigned short* __restrict__ Xn,
    unsigned short* __restrict__ wqb, unsigned short* __restrict__ wkb,
    unsigned short* __restrict__ wvt, float* __restrict__ sums)
{
  const int b = blockIdx.x;          // 0..2047
  const int t = threadIdx.x;
  __shared__ unsigned long long ldsw[256];
  __shared__ int mode1;

  if (t == 0) mode1 = 0;
  __syncthreads();
  const unsigned int* m32 = (const unsigned int*)m;
  unsigned int pw = m32[(size_t)b * 4096 + t];
  if (pw & 0x0000ff00u) mode1 = 1;   // benign race
  __syncthreads();

  {
    const int wv_ = t >> 6;
    const int l = t & 63;
    const long gbase = (long)b * 256 + wv_ * 64;
    if (mode1) {
#pragma unroll
      for (int i = 0; i < 4; ++i) {
        const uint4 v = *(const uint4*)(m + ((size_t)(gbase + i * 16) * 64) + (size_t)l * 16);
        unsigned int ws_[4] = {v.x, v.y, v.z, v.w};
        unsigned int bits16 = 0;
#pragma unroll
        for (int q = 0; q < 4; ++q)
#pragma unroll
          for (int bb = 0; bb < 4; ++bb)
            if ((ws_[q] >> (8 * bb)) & 0xffu) bits16 |= 1u << (q * 4 + bb);
        unsigned long long part = (unsigned long long)bits16 << (16 * (l & 3));
        part |= __shfl_xor(part, 1);
        part |= __shfl_xor(part, 2);
        if ((l & 3) == 0) ldsw[wv_ * 64 + i * 16 + (l >> 2)] = part;
      }
    } else {
#pragma unroll
      for (int i = 0; i < 16; ++i) {
        const uint4 v = *(const uint4*)(m32 + ((size_t)(gbase + i * 4) * 64) + (size_t)l * 4);
        unsigned int nib = (v.x ? 1u : 0u) | (v.y ? 2u : 0u) |
                           (v.z ? 4u : 0u) | (v.w ? 8u : 0u);
        unsigned long long part = (unsigned long long)nib << (4 * (l & 15));
        part |= __shfl_xor(part, 1);
        part |= __shfl_xor(part, 2);
        part |= __shfl_xor(part, 4);
        part |= __shfl_xor(part, 8);
        if ((l & 15) == 0) ldsw[wv_ * 64 + i * 4 + (l >> 4)] = part;
      }
    }
  }
  __syncthreads();
  pm[(long)b * 256 + t] = ldsw[t];

  {
    const int stride = 2048 * 256;
#pragma unroll
    for (int r = 0; r < 8; ++r) {
      int i = b * 256 + t + r * stride;
      const float* src;
      unsigned short* dst;
      int j;
      if (i < 2097152) { src = query; dst = Xq; j = i; }
      else             { src = node;  dst = Xn; j = i - 2097152; }
      float4 v = ((const float4*)src)[j];
      ushort4 o;
      o.x = f2bf(v.x); o.y = f2bf(v.y); o.z = f2bf(v.z); o.w = f2bf(v.w);
      ((ushort4*)dst)[j] = o;
    }
  }

  for (int idx = b * 256 + t; idx < 786432; idx += 2048 * 256) {
    int w = idx >> 18;
    int rem = idx & 262143;
    if (w == 0)      wqb[rem] = f2bf(wq[rem]);
    else if (w == 1) wkb[rem] = f2bf(wk[rem]);
    else {
      int n = rem >> 9, k = rem & 511;
      wvt[n * 512 + k] = f2bf(wv[k * 512 + n]);
    }
  }

  {
    int idx = b * 256 + t;
    if (idx < 16384) sums[idx] = 0.0f;
  }
}

// ---------------------------------------------------------------------------
// Unified 128x128 core, 3 blocks/CU (r12/r14/r15-verified). bf16 out.
// Kept for the tiny MT GEMM only.
__device__ __forceinline__ void core128(
    const unsigned short* __restrict__ Ab, const unsigned short* __restrict__ Bb,
    void* __restrict__ Cb, long ldA, long ldB, long ldO, int nk,
    long bm, long bn, char* smem)
{
  const int tid = threadIdx.x;
  const int lane = tid & 63;
  const int wid = tid >> 6;
  const int wr = wid >> 1, wc = wid & 1;
  const int fr = lane & 15, fq = lane >> 4;

  const int srow = tid >> 2;
  const int sch = (tid & 3) ^ ((srow >> 1) & 3);

  char* bufs[3] = { smem, smem + 16384, smem + 32768 };

#define STAGE_C(buf, kt) do { \
    const long k0_ = (long)(kt) << 5; \
    GLD16(Ab + (bm + srow) * ldA + k0_ + sch * 8,        (buf) + tid * 16); \
    GLD16(Ab + (bm + 64 + srow) * ldA + k0_ + sch * 8,   (buf) + 4096 + tid * 16); \
    GLD16(Bb + (bn + srow) * ldB + k0_ + sch * 8,        (buf) + 8192 + tid * 16); \
    GLD16(Bb + (bn + 64 + srow) * ldB + k0_ + sch * 8,   (buf) + 12288 + tid * 16); \
  } while (0)

  int aoff[4], boff[4];
#pragma unroll
  for (int i = 0; i < 4; ++i) {
    const int ra = wr * 64 + i * 16 + fr;
    aoff[i] = ra * 64 + (fq ^ ((ra >> 1) & 3)) * 16;
    const int rb = wc * 64 + i * 16 + fr;
    boff[i] = 8192 + rb * 64 + (fq ^ ((rb >> 1) & 3)) * 16;
  }

  f32x4 acc[4][4] = {};

  STAGE_C(bufs[0], 0);
  STAGE_C(bufs[1], 1);
  char* c0 = bufs[0]; char* c1 = bufs[1]; char* c2 = bufs[2];

  for (int t = 0; t < nk; ++t) {
    __builtin_amdgcn_sched_barrier(0);
    __builtin_amdgcn_s_barrier();
    if (t + 2 < nk) {
      STAGE_C(c2, t + 2);
      asm volatile("s_waitcnt vmcnt(8)" ::: "memory");
    } else if (t + 2 == nk) {
      asm volatile("s_waitcnt vmcnt(4)" ::: "memory");
    } else {
      asm volatile("s_waitcnt vmcnt(0)" ::: "memory");
    }
    __builtin_amdgcn_s_barrier();
    __builtin_amdgcn_sched_barrier(0);

    bf16x8 a[4];
#pragma unroll
    for (int mi = 0; mi < 4; ++mi)
      a[mi] = *(const bf16x8*)(c0 + aoff[mi]);
    __builtin_amdgcn_s_setprio(1);
#pragma unroll
    for (int nj = 0; nj < 4; ++nj) {
      const bf16x8 b = *(const bf16x8*)(c0 + boff[nj]);
#pragma unroll
      for (int mi = 0; mi < 4; ++mi)
        acc[mi][nj] = __builtin_amdgcn_mfma_f32_16x16x32_bf16(a[mi], b, acc[mi][nj], 0, 0, 0);
    }
    __builtin_amdgcn_s_setprio(0);

    char* tmp = c0; c0 = c1; c1 = c2; c2 = tmp;
  }
#undef STAGE_C

  unsigned short* C = (unsigned short*)Cb;
#pragma unroll
  for (int mi = 0; mi < 4; ++mi)
#pragma unroll
    for (int nj = 0; nj < 4; ++nj) {
      const long row = bm + wr * 64 + mi * 16 + fq * 4;
      const long col = bn + wc * 64 + nj * 16 + fr;
#pragma unroll
      for (int r = 0; r < 4; ++r)
        C[(row + r) * ldO + col] = f2bf(acc[mi][nj][r]);
    }
}

// ---------------------------------------------------------------------------
// Wide core (r22/r23-verified): 128(A) x 256(B) tile, BK=32, 4 waves,
// acc[4][8] = 32 MFMA/barrier-pair, 3 bufs x 24KB = 72KB -> 2 blocks/CU.
// Stage t+2; vmcnt ledger 12/6/0 (L=6).
// mode 0: bf16 out. mode 1: scores epilogue. mode 2: f32 /sums[row].
__device__ __forceinline__ void core_wide(
    const unsigned short* __restrict__ Ab, const unsigned short* __restrict__ Bb,
    void* __restrict__ Cb, long ldA, long ldB, long ldO, int nk,
    long bm, long bn, char* smem, int mode,
    const unsigned long long* __restrict__ pmask, float* __restrict__ sumz,
    const float* __restrict__ sums_ro)
{
  const int tid = threadIdx.x;
  const int lane = tid & 63;
  const int wid = tid >> 6;
  const int wr = wid >> 1, wc = wid & 1;
  const int fr = lane & 15, fq = lane >> 4;

  const int srow = tid >> 2;                    // 0..63
  const int sch = (tid & 3) ^ ((srow >> 1) & 3);

  char* bufs[3] = { smem, smem + 24576, smem + 49152 };

#define STAGE_W(buf, kt) do { \
    const long k0_ = (long)(kt) << 5; \
    GLD16(Ab + (bm + srow) * ldA + k0_ + sch * 8,        (buf) + tid * 16); \
    GLD16(Ab + (bm + 64 + srow) * ldA + k0_ + sch * 8,   (buf) + 4096 + tid * 16); \
    GLD16(Bb + (bn + srow) * ldB + k0_ + sch * 8,        (buf) + 8192 + tid * 16); \
    GLD16(Bb + (bn + 64 + srow) * ldB + k0_ + sch * 8,   (buf) + 12288 + tid * 16); \
    GLD16(Bb + (bn + 128 + srow) * ldB + k0_ + sch * 8,  (buf) + 16384 + tid * 16); \
    GLD16(Bb + (bn + 192 + srow) * ldB + k0_ + sch * 8,  (buf) + 20480 + tid * 16); \
  } while (0)

  int aoff[4], boff[8];
#pragma unroll
  for (int i = 0; i < 4; ++i) {
    const int r = wr * 64 + i * 16 + fr;
    aoff[i] = r * 64 + (fq ^ ((r >> 1) & 3)) * 16;
  }
#pragma unroll
  for (int i = 0; i < 8; ++i) {
    const int r = wc * 128 + i * 16 + fr;
    boff[i] = 8192 + r * 64 + (fq ^ ((r >> 1) & 3)) * 16;
  }

  f32x4 acc[4][8] = {};

  STAGE_W(bufs[0], 0);
  STAGE_W(bufs[1], 1);
  char* c0 = bufs[0]; char* c1 = bufs[1]; char* c2 = bufs[2];

  for (int t = 0; t < nk; ++t) {
    __builtin_amdgcn_sched_barrier(0);
    __builtin_amdgcn_s_barrier();               // B1: reads of c2's old tile done
    if (t + 2 < nk) {
      STAGE_W(c2, t + 2);
      asm volatile("s_waitcnt vmcnt(12)" ::: "memory");   // tile t landed
    } else if (t + 2 == nk) {
      asm volatile("s_waitcnt vmcnt(6)" ::: "memory");
    } else {
      asm volatile("s_waitcnt vmcnt(0)" ::: "memory");
    }
    __builtin_amdgcn_s_barrier();               // B2: tile t visible
    __builtin_amdgcn_sched_barrier(0);

    bf16x8 a[4];
#pragma unroll
    for (int mi = 0; mi < 4; ++mi)
      a[mi] = *(const bf16x8*)(c0 + aoff[mi]);
    __builtin_amdgcn_s_setprio(1);
#pragma unroll
    for (int nj = 0; nj < 8; ++nj) {
      const bf16x8 b = *(const bf16x8*)(c0 + boff[nj]);
#pragma unroll
      for (int mi = 0; mi < 4; ++mi)
        acc[mi][nj] = __builtin_amdgcn_mfma_f32_16x16x32_bf16(a[mi], b, acc[mi][nj], 0, 0, 0);
    }
    __builtin_amdgcn_s_setprio(0);

    char* tmp = c0; c0 = c1; c1 = c2; c2 = tmp;
  }
#undef STAGE_W

  // Epilogue. C/D layout: col=lane&15, row=(lane>>4)*4+r  [m89-verified]
  const float SCALE = 0.04419417382415922f;  // 1/sqrt(512)
  if (mode == 0) {
    unsigned short* C = (unsigned short*)Cb;
#pragma unroll
    for (int mi = 0; mi < 4; ++mi) {
      const long rowb = bm + wr * 64 + mi * 16 + fq * 4;
#pragma unroll
      for (int r = 0; r < 4; ++r) {
        const long row = rowb + r;
        unsigned short* Crow = C + row * ldO + bn + wc * 128 + fr;
#pragma unroll
        for (int ni = 0; ni < 8; ++ni)
          Crow[ni * 16] = f2bf(acc[mi][ni][r]);
      }
    }
  } else if (mode == 1) {
    unsigned short* C = (unsigned short*)Cb;
    const long wbase = (bn >> 6) + wc * 2;
#pragma unroll
    for (int mi = 0; mi < 4; ++mi) {
      const long rowb = bm + wr * 64 + mi * 16 + fq * 4;
#pragma unroll
      for (int r = 0; r < 4; ++r) {
        const long row = rowb + r;
        const unsigned long long w0 = pmask[row * 32 + wbase];
        const unsigned long long w1 = pmask[row * 32 + wbase + 1];
        unsigned short* Crow = C + row * ldO + bn + wc * 128 + fr;
        float s = 0.f;
#pragma unroll
        for (int ni = 0; ni < 8; ++ni) {
          const unsigned long long w = (ni < 4) ? w0 : w1;
          const int sh = (ni & 3) * 16 + fr;
          float e = ((w >> sh) & 1ull) ? 0.0f : __expf(acc[mi][ni][r] * SCALE);
          s += e;
          Crow[ni * 16] = f2bf(e);
        }
        s += __shfl_xor(s, 1); s += __shfl_xor(s, 2);
        s += __shfl_xor(s, 4); s += __shfl_xor(s, 8);
        if (fr == 0) atomicAdd(&sumz[row], s);
      }
    }
  } else {
    float* C = (float*)Cb;
#pragma unroll
    for (int mi = 0; mi < 4; ++mi) {
      const long rowb = bm + wr * 64 + mi * 16 + fq * 4;
#pragma unroll
      for (int r = 0; r < 4; ++r) {
        const long row = rowb + r;
        const float iv = 1.0f / sums_ro[row];
        float* Crow = C + row * ldO + bn + wc * 128 + fr;
#pragma unroll
        for (int ni = 0; ni < 8; ++ni)
          Crow[ni * 16] = acc[mi][ni][r] * iv;
      }
    }
  }
}

// MT = Wk_bf * Wq_bf^T. grid(4,4,1).
__global__ __launch_bounds__(256, 3) void gemm_mt(
    const unsigned short* __restrict__ wkb, const unsigned short* __restrict__ wqb,
    unsigned short* __restrict__ MT)
{
  extern __shared__ char smem[];
  core128(wkb, wqb, MT, 512, 512, 512, 16,
          (long)blockIdx.x * 128, (long)blockIdx.y * 128, smem);
}

// Projections on the wide core, grid(128,2,2) = 512 blocks = 1 even round:
//  z=0: T = Xq*MT^T [16384x512]: bm=x*128, bn=y*256
//  z=1: Vt = Wvt*Xn^T [512x16384]: flat=x*2+y: bm=(flat>>6)*128, bn=(flat&63)*256
__global__ __launch_bounds__(256, 2) void gemm_proj(
    const unsigned short* __restrict__ Xq, const unsigned short* __restrict__ Xn,
    const unsigned short* __restrict__ MT, const unsigned short* __restrict__ Wvt,
    unsigned short* __restrict__ T, unsigned short* __restrict__ Vt)
{
  extern __shared__ char smem[];
  if (blockIdx.z == 0) {
    core_wide(Xq, MT, T, 512, 512, 512, 16,
              (long)blockIdx.x * 128, (long)blockIdx.y * 256, smem, 0,
              nullptr, nullptr, nullptr);
  } else {
    const int flat = blockIdx.x * 2 + blockIdx.y;   // 0..255
    core_wide(Wvt, Xn, Vt, 512, 512, 16384, 16,
              (long)(flat >> 6) * 128, (long)(flat & 63) * 256, smem, 0,
              nullptr, nullptr, nullptr);
  }
}

// Scores (r22-verified): 128x256 tile. grid(8,16,8): x=batch=XCD, y=q, z=kv.
__global__ __launch_bounds__(256, 2) void gemm_scores(
    const unsigned short* __restrict__ Tg, const unsigned short* __restrict__ Xng,
    unsigned short* __restrict__ Eg, const unsigned long long* __restrict__ pm,
    float* __restrict__ sums)
{
  extern __shared__ char smem[];
  const long z = blockIdx.x;
  core_wide(Tg + z * 1048576, Xng + z * 1048576, Eg + z * 4194304,
            512, 512, 2048, 16,
            (long)blockIdx.y * 128, (long)blockIdx.z * 256, smem, 1,
            pm + z * 65536, sums + z * 2048, nullptr);
}

// PV (r23): O = (E @ V) / rowsum, f32. 128q x 256d tile.
// grid(8,2,16): x=batch=XCD, y=d panel (fastest), z=q panel.
__global__ __launch_bounds__(256, 2) void gemm_pv(
    const unsigned short* __restrict__ E, const unsigned short* __restrict__ Vt,
    const float* __restrict__ sums, float* __restrict__ O)
{
  extern __shared__ char smem[];
  const long z = blockIdx.x;                    // batch = XCD
  core_wide(E + z * 4194304, Vt + z * 2048, O + z * 1048576,
            2048, 16384, 512, 64,
            (long)blockIdx.z * 128, (long)blockIdx.y * 256, smem, 2,
            nullptr, nullptr, sums + z * 2048);
}

// ---------------------------------------------------------------------------
extern "C" void kernel_launch(void* const* d_in, const int* in_sizes, int n_in,
                              void* d_out, int out_size, void* d_ws, size_t ws_size,
                              hipStream_t stream) {
  const float* node  = (const float*)d_in[0];
  const float* query = (const float*)d_in[1];
  const unsigned char* mask = (const unsigned char*)d_in[2];
  const float* wq = (const float*)d_in[3];
  const float* wk = (const float*)d_in[4];
  const float* wv = (const float*)d_in[5];
  float* out = (float*)d_out;

  char* ws = (char*)d_ws;
  unsigned short* T   = (unsigned short*)(ws);
  unsigned short* Xn  = (unsigned short*)(ws + 16777216);
  unsigned short* Vt  = (unsigned short*)(ws + 33554432);
  unsigned short* E   = (unsigned short*)(ws + 50331648);
  unsigned short* Xq  = (unsigned short*)(ws + 50331648);           // dead after T-proj
  unsigned short* wqb = (unsigned short*)(ws + 67108864);
  unsigned short* wkb = (unsigned short*)(ws + 67633152);
  unsigned short* Wvt = (unsigned short*)(ws + 68157440);
  unsigned short* MT  = (unsigned short*)(ws + 68681728);
  float* sums = (float*)(ws + 117440512);
  unsigned long long* pm = (unsigned long long*)(ws + 118489088);

  prep_all<<<2048, 256, 0, stream>>>(mask, pm, query, node, wq, wk, wv,
                                     Xq, Xn, wqb, wkb, Wvt, sums);

  gemm_mt<<<dim3(4, 4, 1), 256, 49152, stream>>>(wkb, wqb, MT);

  // Projections on the wide core: 512 blocks = exactly 1 round at 2/CU
  dim3 gp(128, 2, 2);
  gemm_proj<<<gp, 256, 73728, stream>>>(Xq, Xn, MT, Wvt, T, Vt);

  // Scores: 128x256 tile (r22-verified)
  dim3 gs(8, 16, 8);
  gemm_scores<<<gs, 256, 73728, stream>>>(T, Xn, E, pm, sums);

  // PV: 128x256 tile, d-panel fastest
  dim3 gv(8, 2, 16);
  gemm_pv<<<gv, 256, 73728, stream>>>(E, Vt, sums, out);
}

// Round 28
// 184.727 us; speedup vs baseline: 1.0434x; 1.0020x over previous
//
#include <hip/hip_runtime.h>

typedef __attribute__((ext_vector_type(8))) short bf16x8;
typedef __attribute__((ext_vector_type(4))) float f32x4;

__device__ __forceinline__ unsigned short f2bf(float f) {
  unsigned int u = __builtin_bit_cast(unsigned int, f);
  u += 0x7fffu + ((u >> 16) & 1u);   // RNE
  return (unsigned short)(u >> 16);
}

#define GLD16(gp, lp) __builtin_amdgcn_global_load_lds( \
    (const __attribute__((address_space(1))) unsigned int*)(gp), \
    (__attribute__((address_space(3))) unsigned int*)(lp), 16, 0, 0)

// ---------------------------------------------------------------------------
// Grid-stride prep (r21-verified): wide-load mask pack + converts + weights.
__global__ __launch_bounds__(256) void prep_all(
    const unsigned char* __restrict__ m, unsigned long long* __restrict__ pm,
    const float* __restrict__ query, const float* __restrict__ node,
    const float* __restrict__ wq, const float* __restrict__ wk,
    const float* __restrict__ wv,
    unsigned short* __restrict__ Xq, unsigned short* __restrict__ Xn,
    unsigned short* __restrict__ wqb, unsigned short* __restrict__ wkb,
    unsigned short* __restrict__ wvt, float* __restrict__ sums)
{
  const int b = blockIdx.x;          // 0..2047
  const int t = threadIdx.x;
  __shared__ unsigned long long ldsw[256];
  __shared__ int mode1;

  if (t == 0) mode1 = 0;
  __syncthreads();
  const unsigned int* m32 = (const unsigned int*)m;
  unsigned int pw = m32[(size_t)b * 4096 + t];
  if (pw & 0x0000ff00u) mode1 = 1;   // benign race
  __syncthreads();

  {
    const int wv_ = t >> 6;
    const int l = t & 63;
    const long gbase = (long)b * 256 + wv_ * 64;
    if (mode1) {
#pragma unroll
      for (int i = 0; i < 4; ++i) {
        const uint4 v = *(const uint4*)(m + ((size_t)(gbase + i * 16) * 64) + (size_t)l * 16);
        unsigned int ws_[4] = {v.x, v.y, v.z, v.w};
        unsigned int bits16 = 0;
#pragma unroll
        for (int q = 0; q < 4; ++q)
#pragma unroll
          for (int bb = 0; bb < 4; ++bb)
            if ((ws_[q] >> (8 * bb)) & 0xffu) bits16 |= 1u << (q * 4 + bb);
        unsigned long long part = (unsigned long long)bits16 << (16 * (l & 3));
        part |= __shfl_xor(part, 1);
        part |= __shfl_xor(part, 2);
        if ((l & 3) == 0) ldsw[wv_ * 64 + i * 16 + (l >> 2)] = part;
      }
    } else {
#pragma unroll
      for (int i = 0; i < 16; ++i) {
        const uint4 v = *(const uint4*)(m32 + ((size_t)(gbase + i * 4) * 64) + (size_t)l * 4);
        unsigned int nib = (v.x ? 1u : 0u) | (v.y ? 2u : 0u) |
                           (v.z ? 4u : 0u) | (v.w ? 8u : 0u);
        unsigned long long part = (unsigned long long)nib << (4 * (l & 15));
        part |= __shfl_xor(part, 1);
        part |= __shfl_xor(part, 2);
        part |= __shfl_xor(part, 4);
        part |= __shfl_xor(part, 8);
        if ((l & 15) == 0) ldsw[wv_ * 64 + i * 4 + (l >> 4)] = part;
      }
    }
  }
  __syncthreads();
  pm[(long)b * 256 + t] = ldsw[t];

  {
    const int stride = 2048 * 256;
#pragma unroll
    for (int r = 0; r < 8; ++r) {
      int i = b * 256 + t + r * stride;
      const float* src;
      unsigned short* dst;
      int j;
      if (i < 2097152) { src = query; dst = Xq; j = i; }
      else             { src = node;  dst = Xn; j = i - 2097152; }
      float4 v = ((const float4*)src)[j];
      ushort4 o;
      o.x = f2bf(v.x); o.y = f2bf(v.y); o.z = f2bf(v.z); o.w = f2bf(v.w);
      ((ushort4*)dst)[j] = o;
    }
  }

  for (int idx = b * 256 + t; idx < 786432; idx += 2048 * 256) {
    int w = idx >> 18;
    int rem = idx & 262143;
    if (w == 0)      wqb[rem] = f2bf(wq[rem]);
    else if (w == 1) wkb[rem] = f2bf(wk[rem]);
    else {
      int n = rem >> 9, k = rem & 511;
      wvt[n * 512 + k] = f2bf(wv[k * 512 + n]);
    }
  }

  {
    int idx = b * 256 + t;
    if (idx < 16384) sums[idx] = 0.0f;
  }
}

// ---------------------------------------------------------------------------
// Unified 128x128 core, 3 blocks/CU (r12/r14/r15-verified). bf16 out.
// Kept for the tiny MT GEMM only.
__device__ __forceinline__ void core128(
    const unsigned short* __restrict__ Ab, const unsigned short* __restrict__ Bb,
    void* __restrict__ Cb, long ldA, long ldB, long ldO, int nk,
    long bm, long bn, char* smem)
{
  const int tid = threadIdx.x;
  const int lane = tid & 63;
  const int wid = tid >> 6;
  const int wr = wid >> 1, wc = wid & 1;
  const int fr = lane & 15, fq = lane >> 4;

  const int srow = tid >> 2;
  const int sch = (tid & 3) ^ ((srow >> 1) & 3);

  char* bufs[3] = { smem, smem + 16384, smem + 32768 };

#define STAGE_C(buf, kt) do { \
    const long k0_ = (long)(kt) << 5; \
    GLD16(Ab + (bm + srow) * ldA + k0_ + sch * 8,        (buf) + tid * 16); \
    GLD16(Ab + (bm + 64 + srow) * ldA + k0_ + sch * 8,   (buf) + 4096 + tid * 16); \
    GLD16(Bb + (bn + srow) * ldB + k0_ + sch * 8,        (buf) + 8192 + tid * 16); \
    GLD16(Bb + (bn + 64 + srow) * ldB + k0_ + sch * 8,   (buf) + 12288 + tid * 16); \
  } while (0)

  int aoff[4], boff[4];
#pragma unroll
  for (int i = 0; i < 4; ++i) {
    const int ra = wr * 64 + i * 16 + fr;
    aoff[i] = ra * 64 + (fq ^ ((ra >> 1) & 3)) * 16;
    const int rb = wc * 64 + i * 16 + fr;
    boff[i] = 8192 + rb * 64 + (fq ^ ((rb >> 1) & 3)) * 16;
  }

  f32x4 acc[4][4] = {};

  STAGE_C(bufs[0], 0);
  STAGE_C(bufs[1], 1);
  char* c0 = bufs[0]; char* c1 = bufs[1]; char* c2 = bufs[2];

  for (int t = 0; t < nk; ++t) {
    __builtin_amdgcn_sched_barrier(0);
    __builtin_amdgcn_s_barrier();
    if (t + 2 < nk) {
      STAGE_C(c2, t + 2);
      asm volatile("s_waitcnt vmcnt(8)" ::: "memory");
    } else if (t + 2 == nk) {
      asm volatile("s_waitcnt vmcnt(4)" ::: "memory");
    } else {
      asm volatile("s_waitcnt vmcnt(0)" ::: "memory");
    }
    __builtin_amdgcn_s_barrier();
    __builtin_amdgcn_sched_barrier(0);

    bf16x8 a[4];
#pragma unroll
    for (int mi = 0; mi < 4; ++mi)
      a[mi] = *(const bf16x8*)(c0 + aoff[mi]);
    __builtin_amdgcn_s_setprio(1);
#pragma unroll
    for (int nj = 0; nj < 4; ++nj) {
      const bf16x8 b = *(const bf16x8*)(c0 + boff[nj]);
#pragma unroll
      for (int mi = 0; mi < 4; ++mi)
        acc[mi][nj] = __builtin_amdgcn_mfma_f32_16x16x32_bf16(a[mi], b, acc[mi][nj], 0, 0, 0);
    }
    __builtin_amdgcn_s_setprio(0);

    char* tmp = c0; c0 = c1; c1 = c2; c2 = tmp;
  }
#undef STAGE_C

  unsigned short* C = (unsigned short*)Cb;
#pragma unroll
  for (int mi = 0; mi < 4; ++mi)
#pragma unroll
    for (int nj = 0; nj < 4; ++nj) {
      const long row = bm + wr * 64 + mi * 16 + fq * 4;
      const long col = bn + wc * 64 + nj * 16 + fr;
#pragma unroll
      for (int r = 0; r < 4; ++r)
        C[(row + r) * ldO + col] = f2bf(acc[mi][nj][r]);
    }
}

// ---------------------------------------------------------------------------
// Wide core (r22/r23-verified): 128(A) x 256(B) tile, BK=32, 4 waves,
// acc[4][8] = 32 MFMA/barrier-pair, 3 bufs x 24KB = 72KB -> 2 blocks/CU.
// Stage t+2; vmcnt ledger 12/6/0 (L=6).
// mode 0: bf16 out. mode 1: scores epilogue. mode 2: f32 /sums[row].
__device__ __forceinline__ void core_wide(
    const unsigned short* __restrict__ Ab, const unsigned short* __restrict__ Bb,
    void* __restrict__ Cb, long ldA, long ldB, long ldO, int nk,
    long bm, long bn, char* smem, int mode,
    const unsigned long long* __restrict__ pmask, float* __restrict__ sumz,
    const float* __restrict__ sums_ro)
{
  const int tid = threadIdx.x;
  const int lane = tid & 63;
  const int wid = tid >> 6;
  const int wr = wid >> 1, wc = wid & 1;
  const int fr = lane & 15, fq = lane >> 4;

  const int srow = tid >> 2;                    // 0..63
  const int sch = (tid & 3) ^ ((srow >> 1) & 3);

  char* bufs[3] = { smem, smem + 24576, smem + 49152 };

#define STAGE_W(buf, kt) do { \
    const long k0_ = (long)(kt) << 5; \
    GLD16(Ab + (bm + srow) * ldA + k0_ + sch * 8,        (buf) + tid * 16); \
    GLD16(Ab + (bm + 64 + srow) * ldA + k0_ + sch * 8,   (buf) + 4096 + tid * 16); \
    GLD16(Bb + (bn + srow) * ldB + k0_ + sch * 8,        (buf) + 8192 + tid * 16); \
    GLD16(Bb + (bn + 64 + srow) * ldB + k0_ + sch * 8,   (buf) + 12288 + tid * 16); \
    GLD16(Bb + (bn + 128 + srow) * ldB + k0_ + sch * 8,  (buf) + 16384 + tid * 16); \
    GLD16(Bb + (bn + 192 + srow) * ldB + k0_ + sch * 8,  (buf) + 20480 + tid * 16); \
  } while (0)

  int aoff[4], boff[8];
#pragma unroll
  for (int i = 0; i < 4; ++i) {
    const int r = wr * 64 + i * 16 + fr;
    aoff[i] = r * 64 + (fq ^ ((r >> 1) & 3)) * 16;
  }
#pragma unroll
  for (int i = 0; i < 8; ++i) {
    const int r = wc * 128 + i * 16 + fr;
    boff[i] = 8192 + r * 64 + (fq ^ ((r >> 1) & 3)) * 16;
  }

  f32x4 acc[4][8] = {};

  STAGE_W(bufs[0], 0);
  STAGE_W(bufs[1], 1);
  char* c0 = bufs[0]; char* c1 = bufs[1]; char* c2 = bufs[2];

  for (int t = 0; t < nk; ++t) {
    __builtin_amdgcn_sched_barrier(0);
    __builtin_amdgcn_s_barrier();               // B1: reads of c2's old tile done
    if (t + 2 < nk) {
      STAGE_W(c2, t + 2);
      asm volatile("s_waitcnt vmcnt(12)" ::: "memory");   // tile t landed
    } else if (t + 2 == nk) {
      asm volatile("s_waitcnt vmcnt(6)" ::: "memory");
    } else {
      asm volatile("s_waitcnt vmcnt(0)" ::: "memory");
    }
    __builtin_amdgcn_s_barrier();               // B2: tile t visible
    __builtin_amdgcn_sched_barrier(0);

    bf16x8 a[4];
#pragma unroll
    for (int mi = 0; mi < 4; ++mi)
      a[mi] = *(const bf16x8*)(c0 + aoff[mi]);
    __builtin_amdgcn_s_setprio(1);
#pragma unroll
    for (int nj = 0; nj < 8; ++nj) {
      const bf16x8 b = *(const bf16x8*)(c0 + boff[nj]);
#pragma unroll
      for (int mi = 0; mi < 4; ++mi)
        acc[mi][nj] = __builtin_amdgcn_mfma_f32_16x16x32_bf16(a[mi], b, acc[mi][nj], 0, 0, 0);
    }
    __builtin_amdgcn_s_setprio(0);

    char* tmp = c0; c0 = c1; c1 = c2; c2 = tmp;
  }
#undef STAGE_W

  // Epilogue. C/D layout: col=lane&15, row=(lane>>4)*4+r  [m89-verified]
  const float SCALE = 0.04419417382415922f;  // 1/sqrt(512)
  if (mode == 0) {
    unsigned short* C = (unsigned short*)Cb;
#pragma unroll
    for (int mi = 0; mi < 4; ++mi) {
      const long rowb = bm + wr * 64 + mi * 16 + fq * 4;
#pragma unroll
      for (int r = 0; r < 4; ++r) {
        const long row = rowb + r;
        unsigned short* Crow = C + row * ldO + bn + wc * 128 + fr;
#pragma unroll
        for (int ni = 0; ni < 8; ++ni)
          Crow[ni * 16] = f2bf(acc[mi][ni][r]);
      }
    }
  } else if (mode == 1) {
    unsigned short* C = (unsigned short*)Cb;
    const long wbase = (bn >> 6) + wc * 2;
#pragma unroll
    for (int mi = 0; mi < 4; ++mi) {
      const long rowb = bm + wr * 64 + mi * 16 + fq * 4;
#pragma unroll
      for (int r = 0; r < 4; ++r) {
        const long row = rowb + r;
        const unsigned long long w0 = pmask[row * 32 + wbase];
        const unsigned long long w1 = pmask[row * 32 + wbase + 1];
        unsigned short* Crow = C + row * ldO + bn + wc * 128 + fr;
        float s = 0.f;
#pragma unroll
        for (int ni = 0; ni < 8; ++ni) {
          const unsigned long long w = (ni < 4) ? w0 : w1;
          const int sh = (ni & 3) * 16 + fr;
          float e = ((w >> sh) & 1ull) ? 0.0f : __expf(acc[mi][ni][r] * SCALE);
          s += e;
          Crow[ni * 16] = f2bf(e);
        }
        s += __shfl_xor(s, 1); s += __shfl_xor(s, 2);
        s += __shfl_xor(s, 4); s += __shfl_xor(s, 8);
        if (fr == 0) atomicAdd(&sumz[row], s);
      }
    }
  } else {
    float* C = (float*)Cb;
#pragma unroll
    for (int mi = 0; mi < 4; ++mi) {
      const long rowb = bm + wr * 64 + mi * 16 + fq * 4;
#pragma unroll
      for (int r = 0; r < 4; ++r) {
        const long row = rowb + r;
        const float iv = 1.0f / sums_ro[row];
        float* Crow = C + row * ldO + bn + wc * 128 + fr;
#pragma unroll
        for (int ni = 0; ni < 8; ++ni)
          Crow[ni * 16] = acc[mi][ni][r] * iv;
      }
    }
  }
}

// MT = Wk_bf * Wq_bf^T. grid(4,4,1).
__global__ __launch_bounds__(256, 3) void gemm_mt(
    const unsigned short* __restrict__ wkb, const unsigned short* __restrict__ wqb,
    unsigned short* __restrict__ MT)
{
  extern __shared__ char smem[];
  core128(wkb, wqb, MT, 512, 512, 512, 16,
          (long)blockIdx.x * 128, (long)blockIdx.y * 128, smem);
}

// Projections on the wide core, grid(128,2,2) = 512 blocks = 1 even round:
//  z=0: T = Xq*MT^T [16384x512]: bm=x*128, bn=y*256
//  z=1: Vt = Wvt*Xn^T [512x16384]: flat=x*2+y: bm=(flat>>6)*128, bn=(flat&63)*256
__global__ __launch_bounds__(256, 2) void gemm_proj(
    const unsigned short* __restrict__ Xq, const unsigned short* __restrict__ Xn,
    const unsigned short* __restrict__ MT, const unsigned short* __restrict__ Wvt,
    unsigned short* __restrict__ T, unsigned short* __restrict__ Vt)
{
  extern __shared__ char smem[];
  if (blockIdx.z == 0) {
    core_wide(Xq, MT, T, 512, 512, 512, 16,
              (long)blockIdx.x * 128, (long)blockIdx.y * 256, smem, 0,
              nullptr, nullptr, nullptr);
  } else {
    const int flat = blockIdx.x * 2 + blockIdx.y;   // 0..255
    core_wide(Wvt, Xn, Vt, 512, 512, 16384, 16,
              (long)(flat >> 6) * 128, (long)(flat & 63) * 256, smem, 0,
              nullptr, nullptr, nullptr);
  }
}

// Scores (r22-verified): 128x256 tile. grid(8,16,8): x=batch=XCD, y=q, z=kv.
__global__ __launch_bounds__(256, 2) void gemm_scores(
    const unsigned short* __restrict__ Tg, const unsigned short* __restrict__ Xng,
    unsigned short* __restrict__ Eg, const unsigned long long* __restrict__ pm,
    float* __restrict__ sums)
{
  extern __shared__ char smem[];
  const long z = blockIdx.x;
  core_wide(Tg + z * 1048576, Xng + z * 1048576, Eg + z * 4194304,
            512, 512, 2048, 16,
            (long)blockIdx.y * 128, (long)blockIdx.z * 256, smem, 1,
            pm + z * 65536, sums + z * 2048, nullptr);
}

// PV (r23): O = (E @ V) / rowsum, f32. 128q x 256d tile.
// grid(8,2,16): x=batch=XCD, y=d panel (fastest), z=q panel.
__global__ __launch_bounds__(256, 2) void gemm_pv(
    const unsigned short* __restrict__ E, const unsigned short* __restrict__ Vt,
    const float* __restrict__ sums, float* __restrict__ O)
{
  extern __shared__ char smem[];
  const long z = blockIdx.x;                    // batch = XCD
  core_wide(E + z * 4194304, Vt + z * 2048, O + z * 1048576,
            2048, 16384, 512, 64,
            (long)blockIdx.z * 128, (long)blockIdx.y * 256, smem, 2,
            nullptr, nullptr, sums + z * 2048);
}

// ---------------------------------------------------------------------------
extern "C" void kernel_launch(void* const* d_in, const int* in_sizes, int n_in,
                              void* d_out, int out_size, void* d_ws, size_t ws_size,
                              hipStream_t stream) {
  const float* node  = (const float*)d_in[0];
  const float* query = (const float*)d_in[1];
  const unsigned char* mask = (const unsigned char*)d_in[2];
  const float* wq = (const float*)d_in[3];
  const float* wk = (const float*)d_in[4];
  const float* wv = (const float*)d_in[5];
  float* out = (float*)d_out;

  char* ws = (char*)d_ws;
  unsigned short* T   = (unsigned short*)(ws);
  unsigned short* Xn  = (unsigned short*)(ws + 16777216);
  unsigned short* Vt  = (unsigned short*)(ws + 33554432);
  unsigned short* E   = (unsigned short*)(ws + 50331648);
  unsigned short* Xq  = (unsigned short*)(ws + 50331648);           // dead after T-proj
  unsigned short* wqb = (unsigned short*)(ws + 67108864);
  unsigned short* wkb = (unsigned short*)(ws + 67633152);
  unsigned short* Wvt = (unsigned short*)(ws + 68157440);
  unsigned short* MT  = (unsigned short*)(ws + 68681728);
  float* sums = (float*)(ws + 117440512);
  unsigned long long* pm = (unsigned long long*)(ws + 118489088);

  prep_all<<<2048, 256, 0, stream>>>(mask, pm, query, node, wq, wk, wv,
                                     Xq, Xn, wqb, wkb, Wvt, sums);

  gemm_mt<<<dim3(4, 4, 1), 256, 49152, stream>>>(wkb, wqb, MT);

  // Projections on the wide core: 512 blocks = exactly 1 round at 2/CU
  dim3 gp(128, 2, 2);
  gemm_proj<<<gp, 256, 73728, stream>>>(Xq, Xn, MT, Wvt, T, Vt);

  // Scores: 128x256 tile (r22-verified)
  dim3 gs(8, 16, 8);
  gemm_scores<<<gs, 256, 73728, stream>>>(T, Xn, E, pm, sums);

  // PV: 128x256 tile, d-panel fastest
  dim3 gv(8, 2, 16);
  gemm_pv<<<gv, 256, 73728, stream>>>(E, Vt, sums, out);
}